// Round 11
// baseline (8022.510 us; speedup 1.0000x reference)
//
#include <hip/hip_runtime.h>

#define NB 64
#define NT 1024
#define DIN 12
#define NH 256
#define NG 1024
#define NCLS 17
#define TCL 128
#define NCHUNK 8
#define XPS ((size_t)2 * NB * TCL * NG)   // floats per xp1 chunk buffer

typedef _Float16 f16;
typedef __attribute__((ext_vector_type(2))) _Float16 half2_t;
typedef __attribute__((ext_vector_type(8))) _Float16 f16x8;
typedef __attribute__((ext_vector_type(4))) float f32x4;
typedef unsigned int uint;
typedef unsigned short ushort;

__device__ __forceinline__ float sigm(float v) { return 1.0f / (1.0f + __expf(-v)); }
__device__ __forceinline__ float tanh_(float v) {
    v = fminf(fmaxf(v, -15.0f), 15.0f);
    float e = __expf(2.0f * v);
    return (e - 1.0f) / (e + 1.0f);
}
__device__ __forceinline__ float dot2(uint w, uint h, float c) {
    return __builtin_amdgcn_fdot2(__builtin_bit_cast(half2_t, w),
                                  __builtin_bit_cast(half2_t, h), c, false);
}
__device__ __forceinline__ uint pack16(float a, float b) {
    union { f16 h[2]; uint u; } cv; cv.h[0] = (f16)a; cv.h[1] = (f16)b; return cv.u;
}
__device__ __forceinline__ uint pkrtz(float a, float b) {
    return __builtin_bit_cast(uint, __builtin_amdgcn_cvt_pkrtz(a, b));
}
__device__ __forceinline__ ushort hbits(f16 v) {
    union { f16 h; ushort u; } cv; cv.h = v; return cv.u;
}
__device__ __forceinline__ uint rdlane(uint v, int l) {
    return (uint)__builtin_amdgcn_readlane((int)v, l);
}

// ---------------------------------------------------------------------------
// k_prep: pack fp16 weights (round-8/10 layouts). ld = layer*2+dir, kp = k/2:
//  Wkv [ld][q][t][kp 0..39]    per-lane contiguous  (VGPR cache, 160 uints)
//  Wka [ld][q][t][kp 40..99]   per-lane contiguous  (AGPR cache, 240 uints)
//  Wkl [ld][q][g 0..6][t]      uint4 (LDS cache, kp = 100+4g+j, 112 KB)
//  wih0p [dir][q][dp 0..5][t]  packed half2 of w_ih0 input pairs (-> VGPRs)
//  wih1h fp16 copy of w_ih1; bsum1 = b_ih1 + b_hh1
// ---------------------------------------------------------------------------
__global__ void k_prep(const float* __restrict__ w_hh0, const float* __restrict__ w_hh1,
                       const float* __restrict__ w_ih0, const float* __restrict__ w_ih1,
                       const float* __restrict__ b_ih1, const float* __restrict__ b_hh1,
                       uint* __restrict__ Wkv, uint* __restrict__ Wka,
                       uint* __restrict__ Wkl, uint* __restrict__ wih0p,
                       f16* __restrict__ wih1h, float* __restrict__ bsum1) {
    int i = blockIdx.x * 256 + threadIdx.x;
    if (i < 4 * 4 * 256 * 40) {            // Wkv: 163840 uints
        int kp = i % 40; int r = i / 40;
        int t = r & 255, q = (r >> 8) & 3, ld = r >> 10;
        const float* row = (ld < 2 ? w_hh0 : w_hh1) + (size_t)(ld & 1) * NG * NH
                         + (size_t)(q * 256 + t) * NH;
        Wkv[i] = pack16(row[2 * kp], row[2 * kp + 1]);
    }
    if (i < 4 * 4 * 256 * 60) {            // Wka: 245760 uints
        int kp = 40 + (i % 60); int r = i / 60;
        int t = r & 255, q = (r >> 8) & 3, ld = r >> 10;
        const float* row = (ld < 2 ? w_hh0 : w_hh1) + (size_t)(ld & 1) * NG * NH
                         + (size_t)(q * 256 + t) * NH;
        Wka[i] = pack16(row[2 * kp], row[2 * kp + 1]);
    }
    if (i < 4 * 4 * 7 * 256 * 4) {         // Wkl: 114688 uints
        int j = i & 3; int u = i >> 2;
        int t = u & 255; int v = u >> 8;
        int g = v % 7; int w2 = v / 7;
        int q = w2 & 3, ld = w2 >> 2;
        int kp = 100 + 4 * g + j;
        const float* row = (ld < 2 ? w_hh0 : w_hh1) + (size_t)(ld & 1) * NG * NH
                         + (size_t)(q * 256 + t) * NH;
        Wkl[i] = pack16(row[2 * kp], row[2 * kp + 1]);
    }
    if (i < 2 * 4 * 6 * 256) {             // wih0p: 12288 uints
        int t = i & 255; int r = i >> 8;
        int dp = r % 6, q = (r / 6) & 3, dd = r / 24;
        const float* row = w_ih0 + ((size_t)dd * NG + q * 256 + t) * DIN;
        wih0p[i] = pack16(row[2 * dp], row[2 * dp + 1]);
    }
    if (i < 2 * NG * 2 * NH) wih1h[i] = (f16)w_ih1[i];
    if (i < 2 * NG) bsum1[i] = b_ih1[i] + b_hh1[i];
}

// ---------------------------------------------------------------------------
// rec_seq<LAYER>: one block per (dir, batch-PAIR), 256 threads (1 wave/SIMD).
// Lane t owns unit t (gate rows t, 256+t, 512+t, 768+t) for TWO batches:
// the resident weights (160 VGPR + 240 AGPR uints + 112 KB LDS) are reused
// across both, and the second batch's independent dot chains fill the
// latency stalls that capped the 1-batch version at ~39% VALUBusy.
// h broadcast: one b128 LDS read per batch, then readlane -> SGPR operand
// of v_dot2 (compile-time lane indices). One barrier per step.
// ---------------------------------------------------------------------------
template <int LAYER>
__device__ void rec_seq(char* smem, int rb, int chunk, int nsteps,
                        const uint* __restrict__ Wkv, const uint* __restrict__ Wka,
                        const uint4* __restrict__ Wkl, const uint* __restrict__ wih0p,
                        const float* __restrict__ b_ih0, const float* __restrict__ b_hh0,
                        const float* __restrict__ x, const float* __restrict__ xp1,
                        f16* __restrict__ out0h,
                        float* __restrict__ hst, float* __restrict__ cst,
                        float* __restrict__ hsm) {
    uint4* wlds4 = (uint4*)smem;                         // [4][7][256] uint4 = 112 KB
    ushort* hs16 = (ushort*)(smem + 114688);             // [2 par][2 batch][256] = 2 KB

    const int tid = threadIdx.x;
    const int dir = rb >> 5;
    const int bp = rb & 31;
    const int b0 = 2 * bp, b1 = 2 * bp + 1;
    const int ld = LAYER * 2 + dir;

    // LDS weight slice (kp 100..127)
    for (int n = tid; n < 7168; n += 256) wlds4[n] = Wkl[ld * 7168 + n];

    // VGPR weight cache (kp 0..39)
    uint4 wrv[4][10];
    #pragma unroll
    for (int q = 0; q < 4; ++q) {
        const uint* src = Wkv + (size_t)((ld * 4 + q) * 256 + tid) * 40;
        #pragma unroll
        for (int m = 0; m < 10; ++m) wrv[q][m] = *(const uint4*)(src + m * 4);
    }

    // AGPR weight cache (kp 40..99): 240 uints per lane
    uint aw[240];
    #pragma unroll
    for (int q = 0; q < 4; ++q) {
        const uint* src = Wka + (size_t)((ld * 4 + q) * 256 + tid) * 60;
        #pragma unroll
        for (int m = 0; m < 15; ++m) {
            uint4 v = *(const uint4*)(src + m * 4);
            asm volatile("v_accvgpr_write_b32 %0, %1" : "=a"(aw[(q * 15 + m) * 4 + 0]) : "v"(v.x));
            asm volatile("v_accvgpr_write_b32 %0, %1" : "=a"(aw[(q * 15 + m) * 4 + 1]) : "v"(v.y));
            asm volatile("v_accvgpr_write_b32 %0, %1" : "=a"(aw[(q * 15 + m) * 4 + 2]) : "v"(v.z));
            asm volatile("v_accvgpr_write_b32 %0, %1" : "=a"(aw[(q * 15 + m) * 4 + 3]) : "v"(v.w));
        }
    }

    // L0: input-projection weights in VGPRs (24 uints/lane) + bias
    uint wihr[24];
    float bias[4] = {0.f, 0.f, 0.f, 0.f};
    if (LAYER == 0) {
        #pragma unroll
        for (int q = 0; q < 4; ++q)
            #pragma unroll
            for (int dp = 0; dp < 6; ++dp)
                wihr[q * 6 + dp] = wih0p[((dir * 4 + q) * 6 + dp) * 256 + tid];
        #pragma unroll
        for (int q = 0; q < 4; ++q)
            bias[q] = b_ih0[dir * NG + q * 256 + tid] + b_hh0[dir * NG + q * 256 + tid];
    }

    const int sidx0 = (ld * NB + b0) * NH + tid;
    const int sidx1 = (ld * NB + b1) * NH + tid;
    float cv0, hv0, hsv0 = 0.f, cv1, hv1, hsv1 = 0.f;
    if (chunk == 0) {
        cv0 = hv0 = cv1 = hv1 = 0.f;
    } else {
        cv0 = cst[sidx0]; hv0 = hst[sidx0];
        cv1 = cst[sidx1]; hv1 = hst[sidx1];
        if (LAYER == 1) {
            hsv0 = hsm[(dir * NB + b0) * NH + tid];
            hsv1 = hsm[(dir * NB + b1) * NH + tid];
        }
    }
    hs16[tid] = hbits((f16)hv0);
    hs16[256 + tid] = hbits((f16)hv1);
    __syncthreads();

    #pragma unroll 1
    for (int it = 0; it < nsteps; ++it) {
        const int par = it & 1;
        // one b128 per batch: this lane's 8 h values (2-way wave aliasing)
        uint4 hvv0 = ((const uint4*)(hs16 + par * 512))[tid & 31];
        uint4 hvv1 = ((const uint4*)(hs16 + par * 512 + 256))[tid & 31];

        float a0[4] = {0.f, 0.f, 0.f, 0.f};
        float a1[4] = {0.f, 0.f, 0.f, 0.f};

        uint xph0[6], xph1[6];
        float4 xq0, xq1;
        if (LAYER == 0) {
            const int t = dir ? (NT - 1 - it) : it;
            const float4* xa = (const float4*)(x + ((size_t)b0 * NT + t) * DIN);
            const float4* xb = (const float4*)(x + ((size_t)b1 * NT + t) * DIN);
            float4 A0 = xa[0], A1 = xa[1], A2 = xa[2];
            float4 B0 = xb[0], B1 = xb[1], B2 = xb[2];
            xph0[0] = pkrtz(A0.x, A0.y); xph0[1] = pkrtz(A0.z, A0.w);
            xph0[2] = pkrtz(A1.x, A1.y); xph0[3] = pkrtz(A1.z, A1.w);
            xph0[4] = pkrtz(A2.x, A2.y); xph0[5] = pkrtz(A2.z, A2.w);
            xph1[0] = pkrtz(B0.x, B0.y); xph1[1] = pkrtz(B0.z, B0.w);
            xph1[2] = pkrtz(B1.x, B1.y); xph1[3] = pkrtz(B1.z, B1.w);
            xph1[4] = pkrtz(B2.x, B2.y); xph1[5] = pkrtz(B2.z, B2.w);
        } else {
            xq0 = *(const float4*)(xp1 + (((size_t)dir * NB + b0) * TCL + it) * NG + tid * 4);
            xq1 = *(const float4*)(xp1 + (((size_t)dir * NB + b1) * TCL + it) * NG + tid * 4);
        }

        // ---- VGPR region: g8 0..9 (kp 0..39) ----
        #pragma unroll
        for (int g8 = 0; g8 < 10; ++g8) {
            uint s00 = rdlane(hvv0.x, g8), s01 = rdlane(hvv0.y, g8);
            uint s02 = rdlane(hvv0.z, g8), s03 = rdlane(hvv0.w, g8);
            uint s10 = rdlane(hvv1.x, g8), s11 = rdlane(hvv1.y, g8);
            uint s12 = rdlane(hvv1.z, g8), s13 = rdlane(hvv1.w, g8);
            #pragma unroll
            for (int q = 0; q < 4; ++q) {
                uint4 w = wrv[q][g8];
                a0[q] = dot2(w.x, s00, a0[q]); a1[q] = dot2(w.x, s10, a1[q]);
                a0[q] = dot2(w.y, s01, a0[q]); a1[q] = dot2(w.y, s11, a1[q]);
                a0[q] = dot2(w.z, s02, a0[q]); a1[q] = dot2(w.z, s12, a1[q]);
                a0[q] = dot2(w.w, s03, a0[q]); a1[q] = dot2(w.w, s13, a1[q]);
            }
        }
        // ---- AGPR region: g8 10..24 (kp 40..99) ----
        #pragma unroll
        for (int m = 0; m < 15; ++m) {
            const int g8 = 10 + m;
            uint s00 = rdlane(hvv0.x, g8), s01 = rdlane(hvv0.y, g8);
            uint s02 = rdlane(hvv0.z, g8), s03 = rdlane(hvv0.w, g8);
            uint s10 = rdlane(hvv1.x, g8), s11 = rdlane(hvv1.y, g8);
            uint s12 = rdlane(hvv1.z, g8), s13 = rdlane(hvv1.w, g8);
            #pragma unroll
            for (int q = 0; q < 4; ++q) {
                uint w0, w1, w2, w3;
                asm volatile("v_accvgpr_read_b32 %0, %1" : "=v"(w0) : "a"(aw[(q * 15 + m) * 4 + 0]));
                asm volatile("v_accvgpr_read_b32 %0, %1" : "=v"(w1) : "a"(aw[(q * 15 + m) * 4 + 1]));
                asm volatile("v_accvgpr_read_b32 %0, %1" : "=v"(w2) : "a"(aw[(q * 15 + m) * 4 + 2]));
                asm volatile("v_accvgpr_read_b32 %0, %1" : "=v"(w3) : "a"(aw[(q * 15 + m) * 4 + 3]));
                a0[q] = dot2(w0, s00, a0[q]); a1[q] = dot2(w0, s10, a1[q]);
                a0[q] = dot2(w1, s01, a0[q]); a1[q] = dot2(w1, s11, a1[q]);
                a0[q] = dot2(w2, s02, a0[q]); a1[q] = dot2(w2, s12, a1[q]);
                a0[q] = dot2(w3, s03, a0[q]); a1[q] = dot2(w3, s13, a1[q]);
            }
        }
        // ---- LDS region: g8 25..31 (kp 100..127) ----
        #pragma unroll
        for (int g = 0; g < 7; ++g) {
            const int g8 = 25 + g;
            uint s00 = rdlane(hvv0.x, g8), s01 = rdlane(hvv0.y, g8);
            uint s02 = rdlane(hvv0.z, g8), s03 = rdlane(hvv0.w, g8);
            uint s10 = rdlane(hvv1.x, g8), s11 = rdlane(hvv1.y, g8);
            uint s12 = rdlane(hvv1.z, g8), s13 = rdlane(hvv1.w, g8);
            #pragma unroll
            for (int q = 0; q < 4; ++q) {
                uint4 w = wlds4[(q * 7 + g) * 256 + tid];
                a0[q] = dot2(w.x, s00, a0[q]); a1[q] = dot2(w.x, s10, a1[q]);
                a0[q] = dot2(w.y, s01, a0[q]); a1[q] = dot2(w.y, s11, a1[q]);
                a0[q] = dot2(w.z, s02, a0[q]); a1[q] = dot2(w.z, s12, a1[q]);
                a0[q] = dot2(w.w, s03, a0[q]); a1[q] = dot2(w.w, s13, a1[q]);
            }
        }

        // ---- activation ----
        float z0[4], z1[4];
        #pragma unroll
        for (int q = 0; q < 4; ++q) { z0[q] = a0[q]; z1[q] = a1[q]; }
        if (LAYER == 0) {
            #pragma unroll
            for (int q = 0; q < 4; ++q) {
                float u0 = bias[q], u1 = bias[q];
                #pragma unroll
                for (int d = 0; d < 6; ++d) {
                    u0 = dot2(wihr[q * 6 + d], xph0[d], u0);
                    u1 = dot2(wihr[q * 6 + d], xph1[d], u1);
                }
                z0[q] += u0; z1[q] += u1;
            }
        } else {
            z0[0] += xq0.x; z0[1] += xq0.y; z0[2] += xq0.z; z0[3] += xq0.w;
            z1[0] += xq1.x; z1[1] += xq1.y; z1[2] += xq1.z; z1[3] += xq1.w;
        }
        cv0 = sigm(z0[1]) * cv0 + sigm(z0[0]) * tanh_(z0[2]);
        hv0 = sigm(z0[3]) * tanh_(cv0);
        cv1 = sigm(z1[1]) * cv1 + sigm(z1[0]) * tanh_(z1[2]);
        hv1 = sigm(z1[3]) * tanh_(cv1);
        if (LAYER == 1) { hsv0 += hv0; hsv1 += hv1; }

        f16 hi0 = (f16)hv0, hi1 = (f16)hv1;
        ushort* wo = hs16 + (par ^ 1) * 512;
        wo[tid] = hbits(hi0);
        wo[256 + tid] = hbits(hi1);
        if (LAYER == 0) {
            const int t = dir ? (NT - 1 - it) : it;
            out0h[((size_t)b0 * NT + t) * 512 + dir * 256 + tid] = hi0;
            out0h[((size_t)b1 * NT + t) * 512 + dir * 256 + tid] = hi1;
        }
        __syncthreads();
    }

    cst[sidx0] = cv0; hst[sidx0] = hv0;
    cst[sidx1] = cv1; hst[sidx1] = hv1;
    if (LAYER == 1) {
        hsm[(dir * NB + b0) * NH + tid] = hsv0;
        hsm[(dir * NB + b1) * NH + tid] = hsv1;
    }
}

// ---------------------------------------------------------------------------
// proj_role (chunk c): fp16 MFMA 16x16x32 direct-from-global (layout verified
// rounds 6-10). 128 role-blocks x 4 waves; wave handles 2 m-tiles. Stores xp1
// as [t][unit][gate] so rec1's per-step fetch is one coalesced float4.
// ---------------------------------------------------------------------------
__device__ void proj_role(int pb, int c,
                          const f16* __restrict__ out0h, const f16* __restrict__ wih1h,
                          const float* __restrict__ bsum1, float* __restrict__ xp1) {
    const int tid = threadIdx.x;
    const int w = tid >> 6, l = tid & 63;
    const int lane16 = l & 15, quad = l >> 4;

    #pragma unroll 1
    for (int mi = 0; mi < 2; ++mi) {
        const int mtg = pb * 8 + w * 2 + mi;       // 0..1023
        const int dirt = mtg >> 9;
        const int mtl = mtg & 511;

        const int ra = mtl * 16 + lane16;          // row over b(64) x tl(128)
        const int ab = ra >> 7, tla = ra & 127;
        const int ta = dirt ? (NT - 1 - c * TCL - tla) : (c * TCL + tla);
        const f16* Arow = out0h + ((size_t)ab * NT + ta) * 512 + quad * 8;

        uint4 afr[16];
        #pragma unroll
        for (int kt = 0; kt < 16; ++kt) afr[kt] = *(const uint4*)(Arow + kt * 32);

        int ob[4], otl[4];
        #pragma unroll
        for (int reg = 0; reg < 4; ++reg) {
            int rr = mtl * 16 + quad * 4 + reg;
            ob[reg] = rr >> 7; otl[reg] = rr & 127;
        }

        const f16* Bbase = wih1h + (size_t)dirt * NG * 512 + quad * 8;

        #pragma unroll 1
        for (int nt = 0; nt < 64; ++nt) {
            const int col = nt * 16 + lane16;
            const f16* Brow = Bbase + (size_t)col * 512;
            float bias = bsum1[dirt * NG + col];

            f32x4 acc = {0.f, 0.f, 0.f, 0.f};
            #pragma unroll
            for (int kt = 0; kt < 16; ++kt) {
                uint4 bv = *(const uint4*)(Brow + kt * 32);
                acc = __builtin_amdgcn_mfma_f32_16x16x32_f16(
                    __builtin_bit_cast(f16x8, afr[kt]),
                    __builtin_bit_cast(f16x8, bv), acc, 0, 0, 0);
            }
            const int ucol = col & 255, qcol = col >> 8;
            #pragma unroll
            for (int reg = 0; reg < 4; ++reg) {
                xp1[((size_t)(dirt * NB + ob[reg]) * TCL + otl[reg]) * NG
                    + ucol * 4 + qcol] = acc[reg] + bias;
            }
        }
    }
}

// ---------------------------------------------------------------------------
// Phase A: layer 0, full 1024 steps, 64 blocks (2 sequences each).
// ---------------------------------------------------------------------------
__global__ __launch_bounds__(256, 1) void k_rec0(
    const uint* __restrict__ Wkv, const uint* __restrict__ Wka,
    const uint4* __restrict__ Wkl, const uint* __restrict__ wih0p,
    const float* __restrict__ b_ih0, const float* __restrict__ b_hh0,
    const float* __restrict__ x, f16* __restrict__ out0h,
    float* __restrict__ hst, float* __restrict__ cst) {
    extern __shared__ __align__(16) char smem[];
    rec_seq<0>(smem, blockIdx.x, 0, NT, Wkv, Wka, Wkl, wih0p, b_ih0, b_hh0,
               x, nullptr, out0h, hst, cst, nullptr);
}

// ---------------------------------------------------------------------------
// Phase B launch j: blocks 0..63 = rec1 chunk j-1 (2 seqs each); blocks
// 64..191 = proj chunk j (legal: out0h complete after A). Double-buffered xp1.
// ---------------------------------------------------------------------------
__global__ __launch_bounds__(256, 1) void k_pipe(
    int j,
    const uint* __restrict__ Wkv, const uint* __restrict__ Wka,
    const uint4* __restrict__ Wkl,
    const f16* __restrict__ out0h, const f16* __restrict__ wih1h,
    const float* __restrict__ bsum1, float* __restrict__ xp1,
    float* __restrict__ hst, float* __restrict__ cst, float* __restrict__ hsm) {
    extern __shared__ __align__(16) char smem[];
    const int bid = blockIdx.x;
    if (bid < 64) {
        const int cc = j - 1;
        if (cc >= 0 && cc < NCHUNK)
            rec_seq<1>(smem, bid, cc, TCL, Wkv, Wka, Wkl, nullptr, nullptr, nullptr,
                       nullptr, xp1 + (size_t)(cc & 1) * XPS, nullptr, hst, cst, hsm);
    } else {
        const int cp = j;
        if (cp < NCHUNK)
            proj_role(bid - 64, cp, out0h, wih1h, bsum1,
                      xp1 + (size_t)(cp & 1) * XPS);
    }
}

// ---------------------------------------------------------------------------
__global__ void k_fc(const float* __restrict__ hsm, const float* __restrict__ fc_w,
                     const float* __restrict__ fc_b, float* __restrict__ out) {
    const int b = blockIdx.x;
    const int n = threadIdx.x;
    if (n >= NCLS) return;
    float acc = fc_b[n];
    const float inv = 1.0f / (float)NT;
    for (int k = 0; k < 2 * NH; ++k) {
        float pv = hsm[((k >> 8) * NB + b) * NH + (k & 255)];
        acc += (pv * inv) * fc_w[n * 2 * NH + k];
    }
    out[b * NCLS + n] = acc;
}

// ---------------------------------------------------------------------------
extern "C" void kernel_launch(void* const* d_in, const int* in_sizes, int n_in,
                              void* d_out, int out_size, void* d_ws, size_t ws_size,
                              hipStream_t stream) {
    const float* x     = (const float*)d_in[0];
    const float* w_ih0 = (const float*)d_in[1];
    const float* w_hh0 = (const float*)d_in[2];
    const float* b_ih0 = (const float*)d_in[3];
    const float* b_hh0 = (const float*)d_in[4];
    const float* w_ih1 = (const float*)d_in[5];
    const float* w_hh1 = (const float*)d_in[6];
    const float* b_ih1 = (const float*)d_in[7];
    const float* b_hh1 = (const float*)d_in[8];
    const float* fc_w  = (const float*)d_in[9];
    const float* fc_b  = (const float*)d_in[10];
    float* out = (float*)d_out;

    char* ws = (char*)d_ws;
    uint* Wkv   = (uint*)ws;                      // 163840 u
    uint* Wka   = Wkv + 163840;                   // 245760 u
    uint* Wkl   = Wka + 245760;                   // 114688 u
    uint* wih0p = Wkl + 114688;                   // 12288 u
    f16* wih1h  = (f16*)(wih0p + 12288);          // 1048576 h = 2 MB
    float* bsum1 = (float*)(wih1h + 1048576);     // 2048 f
    float* hst  = bsum1 + 2048;                   // 65536 f
    float* cst  = hst + 65536;                    // 65536 f
    float* hsm  = cst + 65536;                    // 32768 f
    float* xp1  = hsm + 32768;                    // 2 x 16777216 f = 128 MB
    f16* out0h  = (f16*)(xp1 + 2 * XPS);          // 33554432 h = 64 MB

    k_prep<<<dim3(4096), dim3(256), 0, stream>>>(
        w_hh0, w_hh1, w_ih0, w_ih1, b_ih1, b_hh1,
        Wkv, Wka, Wkl, wih0p, wih1h, bsum1);

    k_rec0<<<dim3(64), dim3(256), 116736, stream>>>(
        Wkv, Wka, (const uint4*)Wkl, wih0p, b_ih0, b_hh0, x, out0h, hst, cst);

    for (int j = 0; j <= NCHUNK; ++j) {
        k_pipe<<<dim3(192), dim3(256), 116736, stream>>>(
            j, Wkv, Wka, (const uint4*)Wkl, out0h, wih1h, bsum1, xp1, hst, cst, hsm);
    }

    k_fc<<<dim3(64), dim3(32), 0, stream>>>(hsm, fc_w, fc_b, out);
}

// Round 12
// 4689.567 us; speedup vs baseline: 1.7107x; 1.7107x over previous
//
#include <hip/hip_runtime.h>

#define NB 64
#define NT 1024
#define DIN 12
#define NH 256
#define NG 1024
#define NCLS 17
#define TCL 128
#define NCHUNK 8
#define XPS ((size_t)2 * NB * TCL * NG)   // floats per xp1 chunk buffer

typedef _Float16 f16;
typedef __attribute__((ext_vector_type(2))) _Float16 half2_t;
typedef __attribute__((ext_vector_type(8))) _Float16 f16x8;
typedef __attribute__((ext_vector_type(4))) float f32x4;
typedef unsigned int uint;
typedef unsigned short ushort;

__device__ __forceinline__ float sigm(float v) { return 1.0f / (1.0f + __expf(-v)); }
__device__ __forceinline__ float tanh_(float v) {
    v = fminf(fmaxf(v, -15.0f), 15.0f);
    float e = __expf(2.0f * v);
    return (e - 1.0f) / (e + 1.0f);
}
__device__ __forceinline__ float dot2(uint w, uint h, float c) {
    return __builtin_amdgcn_fdot2(__builtin_bit_cast(half2_t, w),
                                  __builtin_bit_cast(half2_t, h), c, false);
}
__device__ __forceinline__ uint pack16(float a, float b) {
    union { f16 h[2]; uint u; } cv; cv.h[0] = (f16)a; cv.h[1] = (f16)b; return cv.u;
}
__device__ __forceinline__ uint pkrtz(float a, float b) {
    return __builtin_bit_cast(uint, __builtin_amdgcn_cvt_pkrtz(a, b));
}
__device__ __forceinline__ ushort hbits(f16 v) {
    union { f16 h; ushort u; } cv; cv.h = v; return cv.u;
}
__device__ __forceinline__ uint rdlane(uint v, int l) {
    return (uint)__builtin_amdgcn_readlane((int)v, l);
}

// ---------------------------------------------------------------------------
// k_prep: layer-specific fp16 packing. kp = k/2 (0..127).
//  L0 (dir in 0..1):  Wkv0 [dir][q][t][kp 0..39]   (VGPR, 160 uints/lane)
//                     Wka0 [dir][q][t][kp 40..99]  (AGPR, 240 uints/lane)
//                     Wkl0 [dir][q][g 0..6][t]u4   (LDS, kp=100+4g+j, 112 KB)
//                     wih0p [dir][q][dp 0..5][t]   (input-proj pairs -> VGPR)
//  L1:                Wkv1 [dir][q][t][kp 0..47]   (VGPR, 192 uints/lane)
//                     Wka1 [dir][q][t][kp 48..107] (AGPR, 240 uints/lane)
//                     Wkl1 [dir][q][g 0..4][t]u4   (LDS, kp=108+4g+j, 80 KB)
//  wih1h fp16 copy of w_ih1; bsum1 = b_ih1 + b_hh1
// ---------------------------------------------------------------------------
__global__ void k_prep(const float* __restrict__ w_hh0, const float* __restrict__ w_hh1,
                       const float* __restrict__ w_ih0, const float* __restrict__ w_ih1,
                       const float* __restrict__ b_ih1, const float* __restrict__ b_hh1,
                       uint* __restrict__ Wkv0, uint* __restrict__ Wka0,
                       uint* __restrict__ Wkl0, uint* __restrict__ wih0p,
                       uint* __restrict__ Wkv1, uint* __restrict__ Wka1,
                       uint* __restrict__ Wkl1,
                       f16* __restrict__ wih1h, float* __restrict__ bsum1) {
    int i = blockIdx.x * 256 + threadIdx.x;
    // ---- layer 0 ----
    if (i < 2 * 4 * 256 * 40) {            // Wkv0
        int kp = i % 40; int r = i / 40;
        int t = r & 255, q = (r >> 8) & 3, dir = r >> 10;
        const float* row = w_hh0 + (size_t)dir * NG * NH + (size_t)(q * 256 + t) * NH;
        Wkv0[i] = pack16(row[2 * kp], row[2 * kp + 1]);
    }
    if (i < 2 * 4 * 256 * 60) {            // Wka0
        int kp = 40 + (i % 60); int r = i / 60;
        int t = r & 255, q = (r >> 8) & 3, dir = r >> 10;
        const float* row = w_hh0 + (size_t)dir * NG * NH + (size_t)(q * 256 + t) * NH;
        Wka0[i] = pack16(row[2 * kp], row[2 * kp + 1]);
    }
    if (i < 2 * 4 * 7 * 256 * 4) {         // Wkl0
        int j = i & 3; int u = i >> 2;
        int t = u & 255; int v = u >> 8;
        int g = v % 7; int w2 = v / 7;
        int q = w2 & 3, dir = w2 >> 2;
        int kp = 100 + 4 * g + j;
        const float* row = w_hh0 + (size_t)dir * NG * NH + (size_t)(q * 256 + t) * NH;
        Wkl0[i] = pack16(row[2 * kp], row[2 * kp + 1]);
    }
    if (i < 2 * 4 * 6 * 256) {             // wih0p
        int t = i & 255; int r = i >> 8;
        int dp = r % 6, q = (r / 6) & 3, dd = r / 24;
        const float* row = w_ih0 + ((size_t)dd * NG + q * 256 + t) * DIN;
        wih0p[i] = pack16(row[2 * dp], row[2 * dp + 1]);
    }
    // ---- layer 1 ----
    if (i < 2 * 4 * 256 * 48) {            // Wkv1
        int kp = i % 48; int r = i / 48;
        int t = r & 255, q = (r >> 8) & 3, dir = r >> 10;
        const float* row = w_hh1 + (size_t)dir * NG * NH + (size_t)(q * 256 + t) * NH;
        Wkv1[i] = pack16(row[2 * kp], row[2 * kp + 1]);
    }
    if (i < 2 * 4 * 256 * 60) {            // Wka1 (kp 48..107)
        int kp = 48 + (i % 60); int r = i / 60;
        int t = r & 255, q = (r >> 8) & 3, dir = r >> 10;
        const float* row = w_hh1 + (size_t)dir * NG * NH + (size_t)(q * 256 + t) * NH;
        Wka1[i] = pack16(row[2 * kp], row[2 * kp + 1]);
    }
    if (i < 2 * 4 * 5 * 256 * 4) {         // Wkl1 (kp 108..127)
        int j = i & 3; int u = i >> 2;
        int t = u & 255; int v = u >> 8;
        int g = v % 5; int w2 = v / 5;
        int q = w2 & 3, dir = w2 >> 2;
        int kp = 108 + 4 * g + j;
        const float* row = w_hh1 + (size_t)dir * NG * NH + (size_t)(q * 256 + t) * NH;
        Wkl1[i] = pack16(row[2 * kp], row[2 * kp + 1]);
    }
    if (i < 2 * NG * 2 * NH) wih1h[i] = (f16)w_ih1[i];
    if (i < 2 * NG) bsum1[i] = b_ih1[i] + b_hh1[i];
}

// ---------------------------------------------------------------------------
// rec0_seq: layer-0 recurrence (round-10 variant, measured 2.24 us/step).
// One block per (dir,batch), 256 threads. Lane t owns unit t (4 gate rows).
// Weights: 160 VGPR + 240 AGPR uints + 112 KB LDS. h broadcast: one b128
// LDS read/lane + readlane -> SGPR operand of v_dot2. One barrier/step.
// ---------------------------------------------------------------------------
__device__ void rec0_seq(char* smem, int rb,
                         const uint* __restrict__ Wkv0, const uint* __restrict__ Wka0,
                         const uint4* __restrict__ Wkl0, const uint* __restrict__ wih0p,
                         const float* __restrict__ b_ih0, const float* __restrict__ b_hh0,
                         const float* __restrict__ x, f16* __restrict__ out0h,
                         float* __restrict__ hst, float* __restrict__ cst) {
    uint4* wlds4 = (uint4*)smem;                         // [4][7][256] uint4 = 112 KB
    ushort* hs16 = (ushort*)(smem + 114688);             // [2 par][256] f16 = 1 KB

    const int tid = threadIdx.x;
    const int dir = rb >> 6;
    const int b = rb & 63;

    for (int n = tid; n < 7168; n += 256) wlds4[n] = Wkl0[dir * 7168 + n];

    uint4 wrv[4][10];
    #pragma unroll
    for (int q = 0; q < 4; ++q) {
        const uint* src = Wkv0 + (size_t)((dir * 4 + q) * 256 + tid) * 40;
        #pragma unroll
        for (int m = 0; m < 10; ++m) wrv[q][m] = *(const uint4*)(src + m * 4);
    }

    uint aw[240];
    #pragma unroll
    for (int q = 0; q < 4; ++q) {
        const uint* src = Wka0 + (size_t)((dir * 4 + q) * 256 + tid) * 60;
        #pragma unroll
        for (int m = 0; m < 15; ++m) {
            uint4 v = *(const uint4*)(src + m * 4);
            asm volatile("v_accvgpr_write_b32 %0, %1" : "=a"(aw[(q * 15 + m) * 4 + 0]) : "v"(v.x));
            asm volatile("v_accvgpr_write_b32 %0, %1" : "=a"(aw[(q * 15 + m) * 4 + 1]) : "v"(v.y));
            asm volatile("v_accvgpr_write_b32 %0, %1" : "=a"(aw[(q * 15 + m) * 4 + 2]) : "v"(v.z));
            asm volatile("v_accvgpr_write_b32 %0, %1" : "=a"(aw[(q * 15 + m) * 4 + 3]) : "v"(v.w));
        }
    }

    uint wihr[24];
    float bias[4];
    #pragma unroll
    for (int q = 0; q < 4; ++q) {
        #pragma unroll
        for (int dp = 0; dp < 6; ++dp)
            wihr[q * 6 + dp] = wih0p[((dir * 4 + q) * 6 + dp) * 256 + tid];
        bias[q] = b_ih0[dir * NG + q * 256 + tid] + b_hh0[dir * NG + q * 256 + tid];
    }

    const int sidx = (dir * NB + b) * NH + tid;
    float cv = 0.f, hv = 0.f;
    hs16[tid] = hbits((f16)0.f);
    __syncthreads();

    #pragma unroll 1
    for (int it = 0; it < NT; ++it) {
        const int par = it & 1;
        uint4 hvv = ((const uint4*)(hs16 + par * 256))[tid & 31];

        float ah[4] = {0.f, 0.f, 0.f, 0.f};

        const int t = dir ? (NT - 1 - it) : it;
        const float4* xp = (const float4*)(x + ((size_t)b * NT + t) * DIN);
        float4 A = xp[0], B4 = xp[1], C4 = xp[2];
        float xv[12] = {A.x, A.y, A.z, A.w, B4.x, B4.y, B4.z, B4.w,
                        C4.x, C4.y, C4.z, C4.w};

        #pragma unroll
        for (int g8 = 0; g8 < 10; ++g8) {
            uint s0 = rdlane(hvv.x, g8), s1 = rdlane(hvv.y, g8);
            uint s2 = rdlane(hvv.z, g8), s3 = rdlane(hvv.w, g8);
            #pragma unroll
            for (int q = 0; q < 4; ++q) {
                uint4 w = wrv[q][g8];
                ah[q] = dot2(w.x, s0, ah[q]);
                ah[q] = dot2(w.y, s1, ah[q]);
                ah[q] = dot2(w.z, s2, ah[q]);
                ah[q] = dot2(w.w, s3, ah[q]);
            }
        }
        #pragma unroll
        for (int m = 0; m < 15; ++m) {
            const int g8 = 10 + m;
            uint s0 = rdlane(hvv.x, g8), s1 = rdlane(hvv.y, g8);
            uint s2 = rdlane(hvv.z, g8), s3 = rdlane(hvv.w, g8);
            #pragma unroll
            for (int q = 0; q < 4; ++q) {
                uint w0, w1, w2, w3;
                asm volatile("v_accvgpr_read_b32 %0, %1" : "=v"(w0) : "a"(aw[(q * 15 + m) * 4 + 0]));
                asm volatile("v_accvgpr_read_b32 %0, %1" : "=v"(w1) : "a"(aw[(q * 15 + m) * 4 + 1]));
                asm volatile("v_accvgpr_read_b32 %0, %1" : "=v"(w2) : "a"(aw[(q * 15 + m) * 4 + 2]));
                asm volatile("v_accvgpr_read_b32 %0, %1" : "=v"(w3) : "a"(aw[(q * 15 + m) * 4 + 3]));
                ah[q] = dot2(w0, s0, ah[q]);
                ah[q] = dot2(w1, s1, ah[q]);
                ah[q] = dot2(w2, s2, ah[q]);
                ah[q] = dot2(w3, s3, ah[q]);
            }
        }
        #pragma unroll
        for (int g = 0; g < 7; ++g) {
            const int g8 = 25 + g;
            uint s0 = rdlane(hvv.x, g8), s1 = rdlane(hvv.y, g8);
            uint s2 = rdlane(hvv.z, g8), s3 = rdlane(hvv.w, g8);
            #pragma unroll
            for (int q = 0; q < 4; ++q) {
                uint4 w = wlds4[(q * 7 + g) * 256 + tid];
                ah[q] = dot2(w.x, s0, ah[q]);
                ah[q] = dot2(w.y, s1, ah[q]);
                ah[q] = dot2(w.z, s2, ah[q]);
                ah[q] = dot2(w.w, s3, ah[q]);
            }
        }

        float z[4];
        uint xph[6];
        #pragma unroll
        for (int d = 0; d < 6; ++d) xph[d] = pkrtz(xv[2 * d], xv[2 * d + 1]);
        #pragma unroll
        for (int q = 0; q < 4; ++q) {
            float a = bias[q];
            #pragma unroll
            for (int d = 0; d < 6; ++d)
                a = dot2(wihr[q * 6 + d], xph[d], a);
            z[q] = ah[q] + a;
        }
        cv = sigm(z[1]) * cv + sigm(z[0]) * tanh_(z[2]);
        hv = sigm(z[3]) * tanh_(cv);

        f16 hi = (f16)hv;
        hs16[(par ^ 1) * 256 + tid] = hbits(hi);
        out0h[((size_t)b * NT + t) * 512 + dir * 256 + tid] = hi;
        __syncthreads();
    }

    cst[sidx] = cv; hst[sidx] = hv;
}

// ---------------------------------------------------------------------------
// rec1_seq: layer-1 recurrence (round-8 structure, fattened registers).
// One block per (dir,batch), 256 threads. Weights: 192 VGPR + 240 AGPR uints
// + 80 KB LDS (20 b128/step, was 28). h via LDS broadcast reads (32 b128/step,
// the round-8 pattern that measured 1.98 us/step). xq prefetched one full
// step ahead to hide HBM latency. One barrier per step.
// ---------------------------------------------------------------------------
__device__ void rec1_seq(char* smem, int rb, int chunk, int nsteps,
                         const uint* __restrict__ Wkv1, const uint* __restrict__ Wka1,
                         const uint4* __restrict__ Wkl1, const float* __restrict__ xp1,
                         float* __restrict__ hst, float* __restrict__ cst,
                         float* __restrict__ hsm) {
    uint4* wlds4 = (uint4*)smem;                         // [4][5][256] uint4 = 80 KB
    ushort* hs16 = (ushort*)(smem + 81920);              // [2 par][256] f16 = 1 KB

    const int tid = threadIdx.x;
    const int dir = rb >> 6;
    const int b = rb & 63;
    const int ld = 2 + dir;

    for (int n = tid; n < 5120; n += 256) wlds4[n] = Wkl1[dir * 5120 + n];

    uint4 wrv[4][12];
    #pragma unroll
    for (int q = 0; q < 4; ++q) {
        const uint* src = Wkv1 + (size_t)((dir * 4 + q) * 256 + tid) * 48;
        #pragma unroll
        for (int m = 0; m < 12; ++m) wrv[q][m] = *(const uint4*)(src + m * 4);
    }

    uint aw[240];
    #pragma unroll
    for (int q = 0; q < 4; ++q) {
        const uint* src = Wka1 + (size_t)((dir * 4 + q) * 256 + tid) * 60;
        #pragma unroll
        for (int m = 0; m < 15; ++m) {
            uint4 v = *(const uint4*)(src + m * 4);
            asm volatile("v_accvgpr_write_b32 %0, %1" : "=a"(aw[(q * 15 + m) * 4 + 0]) : "v"(v.x));
            asm volatile("v_accvgpr_write_b32 %0, %1" : "=a"(aw[(q * 15 + m) * 4 + 1]) : "v"(v.y));
            asm volatile("v_accvgpr_write_b32 %0, %1" : "=a"(aw[(q * 15 + m) * 4 + 2]) : "v"(v.z));
            asm volatile("v_accvgpr_write_b32 %0, %1" : "=a"(aw[(q * 15 + m) * 4 + 3]) : "v"(v.w));
        }
    }

    const int sidx = (ld * NB + b) * NH + tid;
    float cv, hv, hsv = 0.f;
    if (chunk == 0) { cv = 0.f; hv = 0.f; }
    else {
        cv = cst[sidx]; hv = hst[sidx];
        hsv = hsm[(dir * NB + b) * NH + tid];
    }
    hs16[tid] = hbits((f16)hv);

    const float* xbase = xp1 + ((size_t)dir * NB + b) * TCL * NG + tid * 4;
    float4 xq_cur = *(const float4*)xbase;     // xq for step 0
    __syncthreads();

    #pragma unroll 1
    for (int it = 0; it < nsteps; ++it) {
        const int par = it & 1;
        const uint4* Hh = (const uint4*)(hs16 + par * 256);

        // prefetch next step's gate inputs (full step of latency to hide)
        const int itn = (it + 1 < nsteps) ? (it + 1) : it;
        float4 xq_nxt = *(const float4*)(xbase + (size_t)itn * NG);

        float ah[4] = {0.f, 0.f, 0.f, 0.f};

        // ---- VGPR region: g8 0..11 (kp 0..47) ----
        #pragma unroll
        for (int g8 = 0; g8 < 12; ++g8) {
            uint4 H = Hh[g8];
            #pragma unroll
            for (int q = 0; q < 4; ++q) {
                uint4 w = wrv[q][g8];
                ah[q] = dot2(w.x, H.x, ah[q]);
                ah[q] = dot2(w.y, H.y, ah[q]);
                ah[q] = dot2(w.z, H.z, ah[q]);
                ah[q] = dot2(w.w, H.w, ah[q]);
            }
        }
        // ---- AGPR region: g8 12..26 (kp 48..107) ----
        #pragma unroll
        for (int m = 0; m < 15; ++m) {
            const int g8 = 12 + m;
            uint4 H = Hh[g8];
            #pragma unroll
            for (int q = 0; q < 4; ++q) {
                uint w0, w1, w2, w3;
                asm volatile("v_accvgpr_read_b32 %0, %1" : "=v"(w0) : "a"(aw[(q * 15 + m) * 4 + 0]));
                asm volatile("v_accvgpr_read_b32 %0, %1" : "=v"(w1) : "a"(aw[(q * 15 + m) * 4 + 1]));
                asm volatile("v_accvgpr_read_b32 %0, %1" : "=v"(w2) : "a"(aw[(q * 15 + m) * 4 + 2]));
                asm volatile("v_accvgpr_read_b32 %0, %1" : "=v"(w3) : "a"(aw[(q * 15 + m) * 4 + 3]));
                ah[q] = dot2(w0, H.x, ah[q]);
                ah[q] = dot2(w1, H.y, ah[q]);
                ah[q] = dot2(w2, H.z, ah[q]);
                ah[q] = dot2(w3, H.w, ah[q]);
            }
        }
        // ---- LDS region: g8 27..31 (kp 108..127) ----
        #pragma unroll
        for (int g = 0; g < 5; ++g) {
            const int g8 = 27 + g;
            uint4 H = Hh[g8];
            #pragma unroll
            for (int q = 0; q < 4; ++q) {
                uint4 w = wlds4[(q * 5 + g) * 256 + tid];
                ah[q] = dot2(w.x, H.x, ah[q]);
                ah[q] = dot2(w.y, H.y, ah[q]);
                ah[q] = dot2(w.z, H.z, ah[q]);
                ah[q] = dot2(w.w, H.w, ah[q]);
            }
        }

        float z0 = ah[0] + xq_cur.x;
        float z1 = ah[1] + xq_cur.y;
        float z2 = ah[2] + xq_cur.z;
        float z3 = ah[3] + xq_cur.w;
        cv = sigm(z1) * cv + sigm(z0) * tanh_(z2);
        hv = sigm(z3) * tanh_(cv);
        hsv += hv;

        hs16[(par ^ 1) * 256 + tid] = hbits((f16)hv);
        __syncthreads();
        xq_cur = xq_nxt;
    }

    cst[sidx] = cv; hst[sidx] = hv;
    hsm[(dir * NB + b) * NH + tid] = hsv;
}

// ---------------------------------------------------------------------------
// proj_role (chunk c): fp16 MFMA 16x16x32 direct-from-global (layout verified
// rounds 6-11). 128 role-blocks x 4 waves; wave handles 2 m-tiles. Stores xp1
// as [t][unit][gate] so rec1's per-step fetch is one coalesced float4.
// ---------------------------------------------------------------------------
__device__ void proj_role(int pb, int c,
                          const f16* __restrict__ out0h, const f16* __restrict__ wih1h,
                          const float* __restrict__ bsum1, float* __restrict__ xp1) {
    const int tid = threadIdx.x;
    const int w = tid >> 6, l = tid & 63;
    const int lane16 = l & 15, quad = l >> 4;

    #pragma unroll 1
    for (int mi = 0; mi < 2; ++mi) {
        const int mtg = pb * 8 + w * 2 + mi;       // 0..1023
        const int dirt = mtg >> 9;
        const int mtl = mtg & 511;

        const int ra = mtl * 16 + lane16;          // row over b(64) x tl(128)
        const int ab = ra >> 7, tla = ra & 127;
        const int ta = dirt ? (NT - 1 - c * TCL - tla) : (c * TCL + tla);
        const f16* Arow = out0h + ((size_t)ab * NT + ta) * 512 + quad * 8;

        uint4 afr[16];
        #pragma unroll
        for (int kt = 0; kt < 16; ++kt) afr[kt] = *(const uint4*)(Arow + kt * 32);

        int ob[4], otl[4];
        #pragma unroll
        for (int reg = 0; reg < 4; ++reg) {
            int rr = mtl * 16 + quad * 4 + reg;
            ob[reg] = rr >> 7; otl[reg] = rr & 127;
        }

        const f16* Bbase = wih1h + (size_t)dirt * NG * 512 + quad * 8;

        #pragma unroll 1
        for (int nt = 0; nt < 64; ++nt) {
            const int col = nt * 16 + lane16;
            const f16* Brow = Bbase + (size_t)col * 512;
            float bias = bsum1[dirt * NG + col];

            f32x4 acc = {0.f, 0.f, 0.f, 0.f};
            #pragma unroll
            for (int kt = 0; kt < 16; ++kt) {
                uint4 bv = *(const uint4*)(Brow + kt * 32);
                acc = __builtin_amdgcn_mfma_f32_16x16x32_f16(
                    __builtin_bit_cast(f16x8, afr[kt]),
                    __builtin_bit_cast(f16x8, bv), acc, 0, 0, 0);
            }
            const int ucol = col & 255, qcol = col >> 8;
            #pragma unroll
            for (int reg = 0; reg < 4; ++reg) {
                xp1[((size_t)(dirt * NB + ob[reg]) * TCL + otl[reg]) * NG
                    + ucol * 4 + qcol] = acc[reg] + bias;
            }
        }
    }
}

// ---------------------------------------------------------------------------
// Phase A: layer 0, full 1024 steps, 128 independent blocks.
// ---------------------------------------------------------------------------
__global__ __launch_bounds__(256, 1) void k_rec0(
    const uint* __restrict__ Wkv0, const uint* __restrict__ Wka0,
    const uint4* __restrict__ Wkl0, const uint* __restrict__ wih0p,
    const float* __restrict__ b_ih0, const float* __restrict__ b_hh0,
    const float* __restrict__ x, f16* __restrict__ out0h,
    float* __restrict__ hst, float* __restrict__ cst) {
    extern __shared__ __align__(16) char smem[];
    rec0_seq(smem, blockIdx.x, Wkv0, Wka0, Wkl0, wih0p, b_ih0, b_hh0,
             x, out0h, hst, cst);
}

// ---------------------------------------------------------------------------
// Phase B launch j: blocks 0..127 = rec1 chunk j-1; blocks 128..255 = proj
// chunk j (legal: out0h complete after phase A). Double-buffered xp1.
// ---------------------------------------------------------------------------
__global__ __launch_bounds__(256, 1) void k_pipe(
    int j,
    const uint* __restrict__ Wkv1, const uint* __restrict__ Wka1,
    const uint4* __restrict__ Wkl1,
    const f16* __restrict__ out0h, const f16* __restrict__ wih1h,
    const float* __restrict__ bsum1, float* __restrict__ xp1,
    float* __restrict__ hst, float* __restrict__ cst, float* __restrict__ hsm) {
    extern __shared__ __align__(16) char smem[];
    const int bid = blockIdx.x;
    if (bid < 128) {
        const int cc = j - 1;
        if (cc >= 0 && cc < NCHUNK)
            rec1_seq(smem, bid, cc, TCL, Wkv1, Wka1, Wkl1,
                     xp1 + (size_t)(cc & 1) * XPS, hst, cst, hsm);
    } else {
        const int cp = j;
        if (cp < NCHUNK)
            proj_role(bid - 128, cp, out0h, wih1h, bsum1,
                      xp1 + (size_t)(cp & 1) * XPS);
    }
}

// ---------------------------------------------------------------------------
__global__ void k_fc(const float* __restrict__ hsm, const float* __restrict__ fc_w,
                     const float* __restrict__ fc_b, float* __restrict__ out) {
    const int b = blockIdx.x;
    const int n = threadIdx.x;
    if (n >= NCLS) return;
    float acc = fc_b[n];
    const float inv = 1.0f / (float)NT;
    for (int k = 0; k < 2 * NH; ++k) {
        float pv = hsm[((k >> 8) * NB + b) * NH + (k & 255)];
        acc += (pv * inv) * fc_w[n * 2 * NH + k];
    }
    out[b * NCLS + n] = acc;
}

// ---------------------------------------------------------------------------
extern "C" void kernel_launch(void* const* d_in, const int* in_sizes, int n_in,
                              void* d_out, int out_size, void* d_ws, size_t ws_size,
                              hipStream_t stream) {
    const float* x     = (const float*)d_in[0];
    const float* w_ih0 = (const float*)d_in[1];
    const float* w_hh0 = (const float*)d_in[2];
    const float* b_ih0 = (const float*)d_in[3];
    const float* b_hh0 = (const float*)d_in[4];
    const float* w_ih1 = (const float*)d_in[5];
    const float* w_hh1 = (const float*)d_in[6];
    const float* b_ih1 = (const float*)d_in[7];
    const float* b_hh1 = (const float*)d_in[8];
    const float* fc_w  = (const float*)d_in[9];
    const float* fc_b  = (const float*)d_in[10];
    float* out = (float*)d_out;

    char* ws = (char*)d_ws;
    uint* Wkv0  = (uint*)ws;                      // 81920 u
    uint* Wka0  = Wkv0 + 81920;                   // 122880 u
    uint* Wkl0  = Wka0 + 122880;                  // 57344 u
    uint* wih0p = Wkl0 + 57344;                   // 12288 u
    uint* Wkv1  = wih0p + 12288;                  // 98304 u
    uint* Wka1  = Wkv1 + 98304;                   // 122880 u
    uint* Wkl1  = Wka1 + 122880;                  // 40960 u
    f16* wih1h  = (f16*)(Wkl1 + 40960);           // 1048576 h = 2 MB
    float* bsum1 = (float*)(wih1h + 1048576);     // 2048 f
    float* hst  = bsum1 + 2048;                   // 65536 f
    float* cst  = hst + 65536;                    // 65536 f
    float* hsm  = cst + 65536;                    // 32768 f
    float* xp1  = hsm + 32768;                    // 2 x 16777216 f = 128 MB
    f16* out0h  = (f16*)(xp1 + 2 * XPS);          // 33554432 h = 64 MB

    k_prep<<<dim3(4096), dim3(256), 0, stream>>>(
        w_hh0, w_hh1, w_ih0, w_ih1, b_ih1, b_hh1,
        Wkv0, Wka0, Wkl0, wih0p, Wkv1, Wka1, Wkl1, wih1h, bsum1);

    k_rec0<<<dim3(128), dim3(256), 115712, stream>>>(
        Wkv0, Wka0, (const uint4*)Wkl0, wih0p, b_ih0, b_hh0, x, out0h, hst, cst);

    for (int j = 0; j <= NCHUNK; ++j) {
        k_pipe<<<dim3(256), dim3(256), 82944, stream>>>(
            j, Wkv1, Wka1, (const uint4*)Wkl1, out0h, wih1h, bsum1,
            xp1, hst, cst, hsm);
    }

    k_fc<<<dim3(64), dim3(32), 0, stream>>>(hsm, fc_w, fc_b, out);
}